// Round 17
// baseline (145.475 us; speedup 1.0000x reference)
//
#include <hip/hip_runtime.h>
#include <hip/hip_bf16.h>

#define B_ 2
#define T_ 2048
#define D_ 1024
#define H_ 16
#define HD_ 64

typedef __attribute__((ext_vector_type(8))) short bf16x8;
typedef __attribute__((ext_vector_type(4))) short bf16x4;
typedef __attribute__((ext_vector_type(4))) float f32x4;
typedef __attribute__((ext_vector_type(4))) unsigned int u32x4;

__device__ __forceinline__ short f2bf(float f) {
  unsigned int u = __builtin_bit_cast(unsigned int, f);
  u += 0x7fffu + ((u >> 16) & 1u);   // round-to-nearest-even
  return (short)(u >> 16);
}

__device__ __forceinline__ unsigned cvtpk(float lo, float hi) {
  unsigned r;
  asm("v_cvt_pk_bf16_f32 %0, %1, %2" : "=v"(r) : "v"(lo), "v"(hi));
  return r;
}

__device__ __forceinline__ float ex2(float x) {   // 2^x, single v_exp_f32
  float r;
  asm("v_exp_f32 %0, %1" : "=v"(r) : "v"(x));
  return r;
}

__device__ __forceinline__ void gl16(const short* g, short* l) {
  __builtin_amdgcn_global_load_lds(
      (const __attribute__((address_space(1))) void*)g,
      (__attribute__((address_space(3))) void*)l, 16, 0, 0);
}

// merged cast: x (4M f32) + Wq|Wk|Wv|Wo (4x 1M f32) -> contiguous bf16 (xb|wqb..wob)
__global__ void cast_all(const float* __restrict__ x,
                         const float* __restrict__ w0, const float* __restrict__ w1,
                         const float* __restrict__ w2, const float* __restrict__ w3,
                         short* __restrict__ out) {
  int i = (blockIdx.x * blockDim.x + threadIdx.x) * 8;   // 0 .. 8M-8
  const float* src;
  int off;
  if (i < 4194304) { src = x; off = i; }
  else {
    int j = i - 4194304;
    int seg = j >> 20;
    src = (seg == 0) ? w0 : (seg == 1) ? w1 : (seg == 2) ? w2 : w3;
    off = j & 1048575;
  }
  float4 a = *(const float4*)(src + off);
  float4 b = *(const float4*)(src + off + 4);
  bf16x8 o;
  o[0] = f2bf(a.x); o[1] = f2bf(a.y); o[2] = f2bf(a.z); o[3] = f2bf(a.w);
  o[4] = f2bf(b.x); o[5] = f2bf(b.y); o[6] = f2bf(b.z); o[7] = f2bf(b.w);
  *(bf16x8*)(out + i) = o;
}

// Fused QKV projection (R12 proven config, reverted from R15): 64x128 BK=64,
// 2-phase counted-vmcnt dbuf, both-sides XOR swizzle, lgkm-drain before closing
// barrier, XCD-rectangle swizzle (16bm x 12bn per XCD). 39 us / ~650 TF —
// structural plateau of the 2-phase family at K=1024 (R9/R11/R13/R14/R15 all worse).
__launch_bounds__(256, 3)
__global__ void gemm_qkv(const short* __restrict__ A, const short* __restrict__ W,
                         const float* __restrict__ bq, const float* __restrict__ bv,
                         short* __restrict__ Qb, short* __restrict__ Kb,
                         short* __restrict__ Vtb) {
  __shared__ short As[2][64 * 64];
  __shared__ short Bs[2][128 * 64];
  const int xcd = blockIdx.x & 7, g = blockIdx.x >> 3;
  const int bm = (xcd >> 1) * 16 + (g & 15);
  const int bn = (xcd & 1) * 12 + (g >> 4);
  const int tid = threadIdx.x, lane = tid & 63, w = tid >> 6;
  const int wr = w >> 1, wc = w & 1;
  const int lrow = lane & 15, lhi = lane >> 4;
  const int srow = lane >> 3, sch = lane & 7;
  const int swz = (lrow & 7) << 3;

  f32x4 acc[2][4] = {};
  auto STAGE = [&](int kt, int buf) {
#pragma unroll
    for (int i = 0; i < 2; ++i) {
      int row = w * 16 + i * 8 + srow;
      gl16(A + (size_t)(bm * 64 + row) * 1024 + kt + ((sch ^ (row & 7)) * 8),
           &As[buf][(w * 16 + i * 8) * 64]);
    }
#pragma unroll
    for (int i = 0; i < 4; ++i) {
      int row = w * 32 + i * 8 + srow;
      gl16(W + (size_t)(bn * 128 + row) * 1024 + kt + ((sch ^ (row & 7)) * 8),
           &Bs[buf][(w * 32 + i * 8) * 64]);
    }
  };

  STAGE(0, 0);
  for (int t = 0; t < 16; ++t) {
    const int buf = t & 1;
    if (t < 15) {
      STAGE((t + 1) * 64, buf ^ 1);
      asm volatile("s_waitcnt vmcnt(6)" ::: "memory");
    } else {
      asm volatile("s_waitcnt vmcnt(0)" ::: "memory");
    }
    __builtin_amdgcn_s_barrier();
    bf16x8 af[2][2], bfr[2][4];
#pragma unroll
    for (int ks = 0; ks < 2; ++ks) {
#pragma unroll
      for (int i = 0; i < 2; ++i)
        af[ks][i] = *(const bf16x8*)(&As[buf][(wr * 32 + i * 16 + lrow) * 64 + ((ks * 32 + lhi * 8) ^ swz)]);
#pragma unroll
      for (int j = 0; j < 4; ++j)
        bfr[ks][j] = *(const bf16x8*)(&Bs[buf][(wc * 64 + j * 16 + lrow) * 64 + ((ks * 32 + lhi * 8) ^ swz)]);
    }
#pragma unroll
    for (int ks = 0; ks < 2; ++ks)
#pragma unroll
      for (int i = 0; i < 2; ++i)
#pragma unroll
        for (int j = 0; j < 4; ++j)
          acc[i][j] = __builtin_amdgcn_mfma_f32_16x16x32_bf16(af[ks][i], bfr[ks][j],
                                                              acc[i][j], 0, 0, 0);
    asm volatile("s_waitcnt lgkmcnt(0)" ::: "memory");   // reads sampled before barrier
    __builtin_amdgcn_s_barrier();
  }

#pragma unroll
  for (int i = 0; i < 2; ++i)
#pragma unroll
    for (int j = 0; j < 4; ++j) {
      const int m0 = bm * 64 + wr * 32 + i * 16 + lhi * 4;
      const int n = bn * 128 + wc * 64 + j * 16 + lrow;
      const int seg = n >> 10, nloc = n & 1023;
      const int h = nloc >> 6, hd = nloc & 63;
      const int b = m0 >> 11, t0 = m0 & 2047;
      if (seg == 0) {
        float bb = bq[nloc];
#pragma unroll
        for (int r = 0; r < 4; ++r)
          Qb[((size_t)(b * H_ + h) * T_ + t0 + r) * HD_ + hd] =
              f2bf((acc[i][j][r] + bb) * 0.180336880f);   // 0.125 * log2(e)
      } else if (seg == 1) {
#pragma unroll
        for (int r = 0; r < 4; ++r)
          Kb[((size_t)(b * H_ + h) * T_ + t0 + r) * HD_ + hd] = f2bf(acc[i][j][r]);
      } else {
        float bb = bv[nloc];
        bf16x4 ov;
#pragma unroll
        for (int r = 0; r < 4; ++r) ov[r] = f2bf(acc[i][j][r] + bb);
        // permuted V storage: kl = wr*32+i*16+lhi*4 -> c = wr*32 + lhi*8 + i*4
        const int c = wr * 32 + lhi * 8 + i * 4;
        *(bf16x4*)(Vtb + ((size_t)(b * H_ + h) * HD_ + hd) * T_ + (t0 & ~63) + c) = ov;
      }
    }
}

// O projection (R12 proven config, untouched): 64x128 BK=64 2-phase dbuf,
// XCD-rectangle swizzle. out[4096,1024] fp32 = A @ Wo^T + bo.
__launch_bounds__(256, 3)
__global__ void gemm_o(const short* __restrict__ A, const short* __restrict__ W,
                       const float* __restrict__ bias, float* __restrict__ out) {
  __shared__ short As[2][64 * 64];
  __shared__ short Bs[2][128 * 64];
  const int xcd = blockIdx.x & 7, g = blockIdx.x >> 3;   // g in 0..63
  const int bm = (xcd >> 1) * 16 + (g & 15);
  const int bn = (xcd & 1) * 4 + (g >> 4);
  const int tid = threadIdx.x, lane = tid & 63, w = tid >> 6;
  const int wr = w >> 1, wc = w & 1;
  const int lrow = lane & 15, lhi = lane >> 4;
  const int srow = lane >> 3, sch = lane & 7;
  const int swz = (lrow & 7) << 3;

  f32x4 acc[2][4] = {};
  auto STAGE = [&](int kt, int buf) {
#pragma unroll
    for (int i = 0; i < 2; ++i) {
      int row = w * 16 + i * 8 + srow;
      gl16(A + (size_t)(bm * 64 + row) * 1024 + kt + ((sch ^ (row & 7)) * 8),
           &As[buf][(w * 16 + i * 8) * 64]);
    }
#pragma unroll
    for (int i = 0; i < 4; ++i) {
      int row = w * 32 + i * 8 + srow;
      gl16(W + (size_t)(bn * 128 + row) * 1024 + kt + ((sch ^ (row & 7)) * 8),
           &Bs[buf][(w * 32 + i * 8) * 64]);
    }
  };

  STAGE(0, 0);
  for (int t = 0; t < 16; ++t) {
    const int buf = t & 1;
    if (t < 15) {
      STAGE((t + 1) * 64, buf ^ 1);
      asm volatile("s_waitcnt vmcnt(6)" ::: "memory");
    } else {
      asm volatile("s_waitcnt vmcnt(0)" ::: "memory");
    }
    __builtin_amdgcn_s_barrier();
    bf16x8 af[2][2], bfr[2][4];
#pragma unroll
    for (int ks = 0; ks < 2; ++ks) {
#pragma unroll
      for (int i = 0; i < 2; ++i)
        af[ks][i] = *(const bf16x8*)(&As[buf][(wr * 32 + i * 16 + lrow) * 64 + ((ks * 32 + lhi * 8) ^ swz)]);
#pragma unroll
      for (int j = 0; j < 4; ++j)
        bfr[ks][j] = *(const bf16x8*)(&Bs[buf][(wc * 64 + j * 16 + lrow) * 64 + ((ks * 32 + lhi * 8) ^ swz)]);
    }
#pragma unroll
    for (int ks = 0; ks < 2; ++ks)
#pragma unroll
      for (int i = 0; i < 2; ++i)
#pragma unroll
        for (int j = 0; j < 4; ++j)
          acc[i][j] = __builtin_amdgcn_mfma_f32_16x16x32_bf16(af[ks][i], bfr[ks][j],
                                                              acc[i][j], 0, 0, 0);
    asm volatile("s_waitcnt lgkmcnt(0)" ::: "memory");
    __builtin_amdgcn_s_barrier();
  }

#pragma unroll
  for (int i = 0; i < 2; ++i)
#pragma unroll
    for (int j = 0; j < 4; ++j) {
      const int m0 = bm * 64 + wr * 32 + i * 16 + lhi * 4;
      const int n = bn * 128 + wc * 64 + j * 16 + lrow;
      const float bb = bias[n];
#pragma unroll
      for (int r = 0; r < 4; ++r)
        out[(size_t)(m0 + r) * 1024 + n] = acc[i][j][r] + bb;
    }
}

// Flash attention v8: QBLK=128 — each block owns 128 q-rows (tile 0..15), each
// wave two 16-row strips (A: w*16, B: 64+w*16). One staged K/V tile + one set
// of kf/vf fragment reads now feeds 32 MFMAs (2x the work per barrier/stage).
// Static softmax P=2^s, both-sides swizzle, register-only P, permuted-V b128.
// Strip diagonals: A at kb=2*tile, B at kb=2*tile+1, same kl>w*16+lrow mask.
__launch_bounds__(256, 4)
__global__ void attn_kernel(const short* __restrict__ Q, const short* __restrict__ K,
                            const short* __restrict__ Vt, short* __restrict__ Ob) {
  __shared__ short Ks_[2][64 * 64];
  __shared__ short Vs_[2][64 * 64];
  const int tid = threadIdx.x, lane = tid & 63, w = tid >> 6;
  const int lrow = lane & 15, lhi = lane >> 4;
  const int bid = blockIdx.x;
  const int bh = (bid & 7) * 4 + ((bid >> 3) & 3);   // 4 bh per XCD
  const int x = bid >> 5, g = x & 7, q = x >> 3;     // x in 0..15
  const int tile = q ? (15 - g) : g;                 // paired rounds: per-CU sum const
  const int b = bh >> 4, h = bh & 15;
  const short* Kbh = K + (size_t)bh * T_ * HD_;
  const short* Vbh = Vt + (size_t)bh * HD_ * T_;

  bf16x8 qfA[2], qfB[2];
#pragma unroll
  for (int ks = 0; ks < 2; ++ks) {
    qfA[ks] = *(const bf16x8*)(Q + ((size_t)bh * T_ + tile * 128 + w * 16 + lrow) * HD_ + ks * 32 + lhi * 8);
    qfB[ks] = *(const bf16x8*)(Q + ((size_t)bh * T_ + tile * 128 + 64 + w * 16 + lrow) * HD_ + ks * 32 + lhi * 8);
  }

  f32x4 oaccA[4] = {}, oaccB[4] = {};
  float lrunA = 0.f, lrunB = 0.f;      // per-lane partial row-sums
  const int qlocal = w * 16 + lrow;    // diagonal predicate for BOTH strips
  const int srow8 = lane >> 3, sch = lane & 7;
  const int swz = (lrow & 7) << 3;

  auto STAGE = [&](int kb, int buf) {
#pragma unroll
    for (int pass = 0; pass < 2; ++pass) {
      int row = pass * 32 + w * 8 + srow8;
      int csrc = (sch ^ (row & 7)) * 8;
      gl16(Kbh + (size_t)(kb * 64 + row) * HD_ + csrc, &Ks_[buf][(pass * 32 + w * 8) * 64]);
      gl16(Vbh + (size_t)row * T_ + kb * 64 + csrc, &Vs_[buf][(pass * 32 + w * 8) * 64]);
    }
  };

  const int kb_last = 2 * tile + 1;    // strip B diagonal; strip A diag at kb_last-1
  STAGE(0, 0);
  int cur = 0;
  for (int kb = 0; kb <= kb_last; ++kb) {
    asm volatile("s_waitcnt vmcnt(0) lgkmcnt(0)" ::: "memory");
    __builtin_amdgcn_s_barrier();
    asm volatile("" ::: "memory");
    const short* Kc = Ks_[cur];
    const short* Vc = Vs_[cur];
    bf16x8 kf[4][2], vf[4][2];
#pragma unroll
    for (int n = 0; n < 4; ++n)
#pragma unroll
      for (int ks = 0; ks < 2; ++ks) {
        kf[n][ks] = *(const bf16x8*)(Kc + (n * 16 + lrow) * 64 + ((ks * 32 + lhi * 8) ^ swz));
        vf[n][ks] = *(const bf16x8*)(Vc + (n * 16 + lrow) * 64 + ((ks * 32 + lhi * 8) ^ swz));
      }
    if (kb < kb_last) STAGE(kb + 1, cur ^ 1);

    const bool actA = (kb <= kb_last - 1);
    // S^T for both strips off the SAME kf
    f32x4 sB[4] = {}, sA[4] = {};
    __builtin_amdgcn_s_setprio(1);
#pragma unroll
    for (int n = 0; n < 4; ++n)
#pragma unroll
      for (int ks = 0; ks < 2; ++ks)
        sB[n] = __builtin_amdgcn_mfma_f32_16x16x32_bf16(kf[n][ks], qfB[ks], sB[n], 0, 0, 0);
    if (actA) {
#pragma unroll
      for (int n = 0; n < 4; ++n)
#pragma unroll
        for (int ks = 0; ks < 2; ++ks)
          sA[n] = __builtin_amdgcn_mfma_f32_16x16x32_bf16(kf[n][ks], qfA[ks], sA[n], 0, 0, 0);
    }
    __builtin_amdgcn_s_setprio(0);

    // diagonal masks (same local predicate for both strips)
    if (kb == kb_last) {
#pragma unroll
      for (int n = 0; n < 4; ++n)
#pragma unroll
        for (int r = 0; r < 4; ++r)
          if (n * 16 + lhi * 4 + r > qlocal) sB[n][r] = -1e9f;
    }
    if (actA && kb == kb_last - 1) {
#pragma unroll
      for (int n = 0; n < 4; ++n)
#pragma unroll
        for (int r = 0; r < 4; ++r)
          if (n * 16 + lhi * 4 + r > qlocal) sA[n][r] = -1e9f;
    }

    // strip B: static softmax + pack + PV
    {
      float p[4][4];
      float ls = 0.f;
#pragma unroll
      for (int n = 0; n < 4; ++n)
#pragma unroll
        for (int r = 0; r < 4; ++r) {
          float e = ex2(sB[n][r]);
          p[n][r] = e;
          ls += e;
        }
      lrunB += ls;
      u32x4 pw0, pw1;
      pw0[0] = cvtpk(p[0][0], p[0][1]); pw0[1] = cvtpk(p[0][2], p[0][3]);
      pw0[2] = cvtpk(p[1][0], p[1][1]); pw0[3] = cvtpk(p[1][2], p[1][3]);
      pw1[0] = cvtpk(p[2][0], p[2][1]); pw1[1] = cvtpk(p[2][2], p[2][3]);
      pw1[2] = cvtpk(p[3][0], p[3][1]); pw1[3] = cvtpk(p[3][2], p[3][3]);
      bf16x8 pf0 = __builtin_bit_cast(bf16x8, pw0);
      bf16x8 pf1 = __builtin_bit_cast(bf16x8, pw1);
      __builtin_amdgcn_s_setprio(1);
#pragma unroll
      for (int j = 0; j < 4; ++j) {
        oaccB[j] = __builtin_amdgcn_mfma_f32_16x16x32_bf16(vf[j][0], pf0, oaccB[j], 0, 0, 0);
        oaccB[j] = __builtin_amdgcn_mfma_f32_16x16x32_bf16(vf[j][1], pf1, oaccB[j], 0, 0, 0);
      }
      __builtin_amdgcn_s_setprio(0);
    }
    // strip A
    if (actA) {
      float p[4][4];
      float ls = 0.f;
#pragma unroll
      for (int n = 0; n < 4; ++n)
#pragma unroll
        for (int r = 0; r < 4; ++r) {
          float e = ex2(sA[n][r]);
          p[n][r] = e;
          ls += e;
        }
      lrunA += ls;
      u32x4 pw0, pw1;
      pw0[0] = cvtpk(p[0][0], p[0][1]); pw0[1] = cvtpk(p[0][2], p[0][3]);
      pw0[2] = cvtpk(p[1][0], p[1][1]); pw0[3] = cvtpk(p[1][2], p[1][3]);
      pw1[0] = cvtpk(p[2][0], p[2][1]); pw1[1] = cvtpk(p[2][2], p[2][3]);
      pw1[2] = cvtpk(p[3][0], p[3][1]); pw1[3] = cvtpk(p[3][2], p[3][3]);
      bf16x8 pf0 = __builtin_bit_cast(bf16x8, pw0);
      bf16x8 pf1 = __builtin_bit_cast(bf16x8, pw1);
      __builtin_amdgcn_s_setprio(1);
#pragma unroll
      for (int j = 0; j < 4; ++j) {
        oaccA[j] = __builtin_amdgcn_mfma_f32_16x16x32_bf16(vf[j][0], pf0, oaccA[j], 0, 0, 0);
        oaccA[j] = __builtin_amdgcn_mfma_f32_16x16x32_bf16(vf[j][1], pf1, oaccA[j], 0, 0, 0);
      }
      __builtin_amdgcn_s_setprio(0);
    }
    cur ^= 1;
  }

  // epilogue: reduce l for each strip, normalize, store
  lrunA += __shfl_xor(lrunA, 16);
  lrunA += __shfl_xor(lrunA, 32);
  lrunB += __shfl_xor(lrunB, 16);
  lrunB += __shfl_xor(lrunB, 32);
  float invA = 1.0f / lrunA, invB = 1.0f / lrunB;
  const int tA = tile * 128 + qlocal, tB = tile * 128 + 64 + qlocal;
#pragma unroll
  for (int j = 0; j < 4; ++j) {
    bf16x4 oA, oB;
#pragma unroll
    for (int r = 0; r < 4; ++r) {
      oA[r] = f2bf(oaccA[j][r] * invA);
      oB[r] = f2bf(oaccB[j][r] * invB);
    }
    *(bf16x4*)(Ob + (size_t)(b * T_ + tA) * D_ + h * 64 + j * 16 + lhi * 4) = oA;
    *(bf16x4*)(Ob + (size_t)(b * T_ + tB) * D_ + h * 64 + j * 16 + lhi * 4) = oB;
  }
}

extern "C" void kernel_launch(void* const* d_in, const int* in_sizes, int n_in,
                              void* d_out, int out_size, void* d_ws, size_t ws_size,
                              hipStream_t stream) {
  const float* x  = (const float*)d_in[0];
  // d_in[1] = mask (causality applied analytically)
  const float* Wq = (const float*)d_in[2];
  const float* bq = (const float*)d_in[3];
  const float* Wk = (const float*)d_in[4];
  const float* Wv = (const float*)d_in[5];
  const float* bv = (const float*)d_in[6];
  const float* Wo = (const float*)d_in[7];
  const float* bo = (const float*)d_in[8];
  float* out = (float*)d_out;

  const int MT = B_ * T_;          // 4096
  short* xb  = (short*)d_ws;                 // [4096,1024]
  short* wqb = xb  + (size_t)MT * D_;        // [3072,1024] contiguous Wq|Wk|Wv
  short* wob = wqb + (size_t)3 * D_ * D_;
  short* Qb  = wob + (size_t)D_ * D_;        // [B,H,T,HD]
  short* Kb  = Qb  + (size_t)MT * D_;
  short* Vtb = Kb  + (size_t)MT * D_;        // [B,H,HD,T] (64-col blocks permuted)
  short* Ab  = Vtb + (size_t)MT * D_;        // [4096,1024]

  cast_all<<<(8 * 1048576) / (256 * 8), 256, 0, stream>>>(x, Wq, Wk, Wv, Wo, xb);

  // fused QKV: C[4096,3072]; Q scale = 0.125 * log2(e) (base-2 softmax)
  gemm_qkv<<<(MT / 64) * 24, 256, 0, stream>>>(xb, wqb, bq, bv, Qb, Kb, Vtb);

  attn_kernel<<<B_ * H_ * 16, 256, 0, stream>>>(Qb, Kb, Vtb, Ab);

  gemm_o<<<(MT / 64) * 8, 256, 0, stream>>>(Ab, wob, bo, out);
}

// Round 18
// 88.528 us; speedup vs baseline: 1.6433x; 1.6433x over previous
//
#include <hip/hip_runtime.h>
#include <hip/hip_bf16.h>

#define B_ 2
#define T_ 2048
#define D_ 1024
#define H_ 16
#define HD_ 64

typedef __attribute__((ext_vector_type(8))) short bf16x8;
typedef __attribute__((ext_vector_type(4))) short bf16x4;
typedef __attribute__((ext_vector_type(4))) float f32x4;
typedef __attribute__((ext_vector_type(4))) unsigned int u32x4;

__device__ __forceinline__ short f2bf(float f) {
  unsigned int u = __builtin_bit_cast(unsigned int, f);
  u += 0x7fffu + ((u >> 16) & 1u);   // round-to-nearest-even
  return (short)(u >> 16);
}

__device__ __forceinline__ unsigned cvtpk(float lo, float hi) {
  unsigned r;
  asm("v_cvt_pk_bf16_f32 %0, %1, %2" : "=v"(r) : "v"(lo), "v"(hi));
  return r;
}

__device__ __forceinline__ float ex2(float x) {   // 2^x, single v_exp_f32
  float r;
  asm("v_exp_f32 %0, %1" : "=v"(r) : "v"(x));
  return r;
}

__device__ __forceinline__ void gl16(const short* g, short* l) {
  __builtin_amdgcn_global_load_lds(
      (const __attribute__((address_space(1))) void*)g,
      (__attribute__((address_space(3))) void*)l, 16, 0, 0);
}

// merged cast: x (4M f32) + Wq|Wk|Wv|Wo (4x 1M f32) -> contiguous bf16 (xb|wqb..wob)
__global__ void cast_all(const float* __restrict__ x,
                         const float* __restrict__ w0, const float* __restrict__ w1,
                         const float* __restrict__ w2, const float* __restrict__ w3,
                         short* __restrict__ out) {
  int i = (blockIdx.x * blockDim.x + threadIdx.x) * 8;   // 0 .. 8M-8
  const float* src;
  int off;
  if (i < 4194304) { src = x; off = i; }
  else {
    int j = i - 4194304;
    int seg = j >> 20;
    src = (seg == 0) ? w0 : (seg == 1) ? w1 : (seg == 2) ? w2 : w3;
    off = j & 1048575;
  }
  float4 a = *(const float4*)(src + off);
  float4 b = *(const float4*)(src + off + 4);
  bf16x8 o;
  o[0] = f2bf(a.x); o[1] = f2bf(a.y); o[2] = f2bf(a.z); o[3] = f2bf(a.w);
  o[4] = f2bf(b.x); o[5] = f2bf(b.y); o[6] = f2bf(b.z); o[7] = f2bf(b.w);
  *(bf16x8*)(out + i) = o;
}

// Fused QKV projection (R12 proven config): 64x128 BK=64, 2-phase counted-vmcnt
// dbuf, both-sides XOR swizzle, lgkm-drain before closing barrier, XCD-rectangle
// swizzle. 39 us / ~650 TF — 2-phase-family plateau at K=1024.
__launch_bounds__(256, 3)
__global__ void gemm_qkv(const short* __restrict__ A, const short* __restrict__ W,
                         const float* __restrict__ bq, const float* __restrict__ bv,
                         short* __restrict__ Qb, short* __restrict__ Kb,
                         short* __restrict__ Vtb) {
  __shared__ short As[2][64 * 64];
  __shared__ short Bs[2][128 * 64];
  const int xcd = blockIdx.x & 7, g = blockIdx.x >> 3;
  const int bm = (xcd >> 1) * 16 + (g & 15);
  const int bn = (xcd & 1) * 12 + (g >> 4);
  const int tid = threadIdx.x, lane = tid & 63, w = tid >> 6;
  const int wr = w >> 1, wc = w & 1;
  const int lrow = lane & 15, lhi = lane >> 4;
  const int srow = lane >> 3, sch = lane & 7;
  const int swz = (lrow & 7) << 3;

  f32x4 acc[2][4] = {};
  auto STAGE = [&](int kt, int buf) {
#pragma unroll
    for (int i = 0; i < 2; ++i) {
      int row = w * 16 + i * 8 + srow;
      gl16(A + (size_t)(bm * 64 + row) * 1024 + kt + ((sch ^ (row & 7)) * 8),
           &As[buf][(w * 16 + i * 8) * 64]);
    }
#pragma unroll
    for (int i = 0; i < 4; ++i) {
      int row = w * 32 + i * 8 + srow;
      gl16(W + (size_t)(bn * 128 + row) * 1024 + kt + ((sch ^ (row & 7)) * 8),
           &Bs[buf][(w * 32 + i * 8) * 64]);
    }
  };

  STAGE(0, 0);
  for (int t = 0; t < 16; ++t) {
    const int buf = t & 1;
    if (t < 15) {
      STAGE((t + 1) * 64, buf ^ 1);
      asm volatile("s_waitcnt vmcnt(6)" ::: "memory");
    } else {
      asm volatile("s_waitcnt vmcnt(0)" ::: "memory");
    }
    __builtin_amdgcn_s_barrier();
    bf16x8 af[2][2], bfr[2][4];
#pragma unroll
    for (int ks = 0; ks < 2; ++ks) {
#pragma unroll
      for (int i = 0; i < 2; ++i)
        af[ks][i] = *(const bf16x8*)(&As[buf][(wr * 32 + i * 16 + lrow) * 64 + ((ks * 32 + lhi * 8) ^ swz)]);
#pragma unroll
      for (int j = 0; j < 4; ++j)
        bfr[ks][j] = *(const bf16x8*)(&Bs[buf][(wc * 64 + j * 16 + lrow) * 64 + ((ks * 32 + lhi * 8) ^ swz)]);
    }
#pragma unroll
    for (int ks = 0; ks < 2; ++ks)
#pragma unroll
      for (int i = 0; i < 2; ++i)
#pragma unroll
        for (int j = 0; j < 4; ++j)
          acc[i][j] = __builtin_amdgcn_mfma_f32_16x16x32_bf16(af[ks][i], bfr[ks][j],
                                                              acc[i][j], 0, 0, 0);
    asm volatile("s_waitcnt lgkmcnt(0)" ::: "memory");   // reads sampled before barrier
    __builtin_amdgcn_s_barrier();
  }

#pragma unroll
  for (int i = 0; i < 2; ++i)
#pragma unroll
    for (int j = 0; j < 4; ++j) {
      const int m0 = bm * 64 + wr * 32 + i * 16 + lhi * 4;
      const int n = bn * 128 + wc * 64 + j * 16 + lrow;
      const int seg = n >> 10, nloc = n & 1023;
      const int h = nloc >> 6, hd = nloc & 63;
      const int b = m0 >> 11, t0 = m0 & 2047;
      if (seg == 0) {
        float bb = bq[nloc];
#pragma unroll
        for (int r = 0; r < 4; ++r)
          Qb[((size_t)(b * H_ + h) * T_ + t0 + r) * HD_ + hd] =
              f2bf((acc[i][j][r] + bb) * 0.180336880f);   // 0.125 * log2(e)
      } else if (seg == 1) {
#pragma unroll
        for (int r = 0; r < 4; ++r)
          Kb[((size_t)(b * H_ + h) * T_ + t0 + r) * HD_ + hd] = f2bf(acc[i][j][r]);
      } else {
        float bb = bv[nloc];
        bf16x4 ov;
#pragma unroll
        for (int r = 0; r < 4; ++r) ov[r] = f2bf(acc[i][j][r] + bb);
        // permuted V storage: kl = wr*32+i*16+lhi*4 -> c = wr*32 + lhi*8 + i*4
        const int c = wr * 32 + lhi * 8 + i * 4;
        *(bf16x4*)(Vtb + ((size_t)(b * H_ + h) * HD_ + hd) * T_ + (t0 & ~63) + c) = ov;
      }
    }
}

// O projection (R12 proven config): 64x128 BK=64 2-phase dbuf, XCD swizzle.
__launch_bounds__(256, 3)
__global__ void gemm_o(const short* __restrict__ A, const short* __restrict__ W,
                       const float* __restrict__ bias, float* __restrict__ out) {
  __shared__ short As[2][64 * 64];
  __shared__ short Bs[2][128 * 64];
  const int xcd = blockIdx.x & 7, g = blockIdx.x >> 3;   // g in 0..63
  const int bm = (xcd >> 1) * 16 + (g & 15);
  const int bn = (xcd & 1) * 4 + (g >> 4);
  const int tid = threadIdx.x, lane = tid & 63, w = tid >> 6;
  const int wr = w >> 1, wc = w & 1;
  const int lrow = lane & 15, lhi = lane >> 4;
  const int srow = lane >> 3, sch = lane & 7;
  const int swz = (lrow & 7) << 3;

  f32x4 acc[2][4] = {};
  auto STAGE = [&](int kt, int buf) {
#pragma unroll
    for (int i = 0; i < 2; ++i) {
      int row = w * 16 + i * 8 + srow;
      gl16(A + (size_t)(bm * 64 + row) * 1024 + kt + ((sch ^ (row & 7)) * 8),
           &As[buf][(w * 16 + i * 8) * 64]);
    }
#pragma unroll
    for (int i = 0; i < 4; ++i) {
      int row = w * 32 + i * 8 + srow;
      gl16(W + (size_t)(bn * 128 + row) * 1024 + kt + ((sch ^ (row & 7)) * 8),
           &Bs[buf][(w * 32 + i * 8) * 64]);
    }
  };

  STAGE(0, 0);
  for (int t = 0; t < 16; ++t) {
    const int buf = t & 1;
    if (t < 15) {
      STAGE((t + 1) * 64, buf ^ 1);
      asm volatile("s_waitcnt vmcnt(6)" ::: "memory");
    } else {
      asm volatile("s_waitcnt vmcnt(0)" ::: "memory");
    }
    __builtin_amdgcn_s_barrier();
    bf16x8 af[2][2], bfr[2][4];
#pragma unroll
    for (int ks = 0; ks < 2; ++ks) {
#pragma unroll
      for (int i = 0; i < 2; ++i)
        af[ks][i] = *(const bf16x8*)(&As[buf][(wr * 32 + i * 16 + lrow) * 64 + ((ks * 32 + lhi * 8) ^ swz)]);
#pragma unroll
      for (int j = 0; j < 4; ++j)
        bfr[ks][j] = *(const bf16x8*)(&Bs[buf][(wc * 64 + j * 16 + lrow) * 64 + ((ks * 32 + lhi * 8) ^ swz)]);
    }
#pragma unroll
    for (int ks = 0; ks < 2; ++ks)
#pragma unroll
      for (int i = 0; i < 2; ++i)
#pragma unroll
        for (int j = 0; j < 4; ++j)
          acc[i][j] = __builtin_amdgcn_mfma_f32_16x16x32_bf16(af[ks][i], bfr[ks][j],
                                                              acc[i][j], 0, 0, 0);
    asm volatile("s_waitcnt lgkmcnt(0)" ::: "memory");
    __builtin_amdgcn_s_barrier();
  }

#pragma unroll
  for (int i = 0; i < 2; ++i)
#pragma unroll
    for (int j = 0; j < 4; ++j) {
      const int m0 = bm * 64 + wr * 32 + i * 16 + lhi * 4;
      const int n = bn * 128 + wc * 64 + j * 16 + lrow;
      const float bb = bias[n];
#pragma unroll
      for (int r = 0; r < 4; ++r)
        out[(size_t)(m0 + r) * 1024 + n] = acc[i][j][r] + bb;
    }
}

// Flash attention v8b: QBLK=128 (R16 structure) with launch_bounds(256,2) —
// VGPR cap 256 removes the spill that sank R16 (VGPR=64, WRITE_SIZE 77MB).
// Each staged K/V tile + fragment read set feeds 32 MFMAs (2x work/barrier).
__launch_bounds__(256, 2)
__global__ void attn_kernel(const short* __restrict__ Q, const short* __restrict__ K,
                            const short* __restrict__ Vt, short* __restrict__ Ob) {
  __shared__ short Ks_[2][64 * 64];
  __shared__ short Vs_[2][64 * 64];
  const int tid = threadIdx.x, lane = tid & 63, w = tid >> 6;
  const int lrow = lane & 15, lhi = lane >> 4;
  const int bid = blockIdx.x;
  const int bh = (bid & 7) * 4 + ((bid >> 3) & 3);   // 4 bh per XCD
  const int x = bid >> 5, g = x & 7, q = x >> 3;     // x in 0..15
  const int tile = q ? (15 - g) : g;                 // paired rounds: per-CU sum const
  const int b = bh >> 4, h = bh & 15;
  const short* Kbh = K + (size_t)bh * T_ * HD_;
  const short* Vbh = Vt + (size_t)bh * HD_ * T_;

  bf16x8 qfA[2], qfB[2];
#pragma unroll
  for (int ks = 0; ks < 2; ++ks) {
    qfA[ks] = *(const bf16x8*)(Q + ((size_t)bh * T_ + tile * 128 + w * 16 + lrow) * HD_ + ks * 32 + lhi * 8);
    qfB[ks] = *(const bf16x8*)(Q + ((size_t)bh * T_ + tile * 128 + 64 + w * 16 + lrow) * HD_ + ks * 32 + lhi * 8);
  }

  f32x4 oaccA[4] = {}, oaccB[4] = {};
  float lrunA = 0.f, lrunB = 0.f;      // per-lane partial row-sums
  const int qlocal = w * 16 + lrow;    // diagonal predicate for BOTH strips
  const int srow8 = lane >> 3, sch = lane & 7;
  const int swz = (lrow & 7) << 3;

  auto STAGE = [&](int kb, int buf) {
#pragma unroll
    for (int pass = 0; pass < 2; ++pass) {
      int row = pass * 32 + w * 8 + srow8;
      int csrc = (sch ^ (row & 7)) * 8;
      gl16(Kbh + (size_t)(kb * 64 + row) * HD_ + csrc, &Ks_[buf][(pass * 32 + w * 8) * 64]);
      gl16(Vbh + (size_t)row * T_ + kb * 64 + csrc, &Vs_[buf][(pass * 32 + w * 8) * 64]);
    }
  };

  const int kb_last = 2 * tile + 1;    // strip B diagonal; strip A diag at kb_last-1
  STAGE(0, 0);
  int cur = 0;
  for (int kb = 0; kb <= kb_last; ++kb) {
    asm volatile("s_waitcnt vmcnt(0) lgkmcnt(0)" ::: "memory");
    __builtin_amdgcn_s_barrier();
    asm volatile("" ::: "memory");
    const short* Kc = Ks_[cur];
    const short* Vc = Vs_[cur];
    bf16x8 kf[4][2], vf[4][2];
#pragma unroll
    for (int n = 0; n < 4; ++n)
#pragma unroll
      for (int ks = 0; ks < 2; ++ks) {
        kf[n][ks] = *(const bf16x8*)(Kc + (n * 16 + lrow) * 64 + ((ks * 32 + lhi * 8) ^ swz));
        vf[n][ks] = *(const bf16x8*)(Vc + (n * 16 + lrow) * 64 + ((ks * 32 + lhi * 8) ^ swz));
      }
    if (kb < kb_last) STAGE(kb + 1, cur ^ 1);

    const bool actA = (kb <= kb_last - 1);
    f32x4 sB[4] = {}, sA[4] = {};
    __builtin_amdgcn_s_setprio(1);
#pragma unroll
    for (int n = 0; n < 4; ++n)
#pragma unroll
      for (int ks = 0; ks < 2; ++ks)
        sB[n] = __builtin_amdgcn_mfma_f32_16x16x32_bf16(kf[n][ks], qfB[ks], sB[n], 0, 0, 0);
    if (actA) {
#pragma unroll
      for (int n = 0; n < 4; ++n)
#pragma unroll
        for (int ks = 0; ks < 2; ++ks)
          sA[n] = __builtin_amdgcn_mfma_f32_16x16x32_bf16(kf[n][ks], qfA[ks], sA[n], 0, 0, 0);
    }
    __builtin_amdgcn_s_setprio(0);

    if (kb == kb_last) {
#pragma unroll
      for (int n = 0; n < 4; ++n)
#pragma unroll
        for (int r = 0; r < 4; ++r)
          if (n * 16 + lhi * 4 + r > qlocal) sB[n][r] = -1e9f;
    }
    if (actA && kb == kb_last - 1) {
#pragma unroll
      for (int n = 0; n < 4; ++n)
#pragma unroll
        for (int r = 0; r < 4; ++r)
          if (n * 16 + lhi * 4 + r > qlocal) sA[n][r] = -1e9f;
    }

    // strip B: static softmax + pack + PV
    {
      float p[4][4];
      float ls = 0.f;
#pragma unroll
      for (int n = 0; n < 4; ++n)
#pragma unroll
        for (int r = 0; r < 4; ++r) {
          float e = ex2(sB[n][r]);
          p[n][r] = e;
          ls += e;
        }
      lrunB += ls;
      u32x4 pw0, pw1;
      pw0[0] = cvtpk(p[0][0], p[0][1]); pw0[1] = cvtpk(p[0][2], p[0][3]);
      pw0[2] = cvtpk(p[1][0], p[1][1]); pw0[3] = cvtpk(p[1][2], p[1][3]);
      pw1[0] = cvtpk(p[2][0], p[2][1]); pw1[1] = cvtpk(p[2][2], p[2][3]);
      pw1[2] = cvtpk(p[3][0], p[3][1]); pw1[3] = cvtpk(p[3][2], p[3][3]);
      bf16x8 pf0 = __builtin_bit_cast(bf16x8, pw0);
      bf16x8 pf1 = __builtin_bit_cast(bf16x8, pw1);
      __builtin_amdgcn_s_setprio(1);
#pragma unroll
      for (int j = 0; j < 4; ++j) {
        oaccB[j] = __builtin_amdgcn_mfma_f32_16x16x32_bf16(vf[j][0], pf0, oaccB[j], 0, 0, 0);
        oaccB[j] = __builtin_amdgcn_mfma_f32_16x16x32_bf16(vf[j][1], pf1, oaccB[j], 0, 0, 0);
      }
      __builtin_amdgcn_s_setprio(0);
    }
    // strip A
    if (actA) {
      float p[4][4];
      float ls = 0.f;
#pragma unroll
      for (int n = 0; n < 4; ++n)
#pragma unroll
        for (int r = 0; r < 4; ++r) {
          float e = ex2(sA[n][r]);
          p[n][r] = e;
          ls += e;
        }
      lrunA += ls;
      u32x4 pw0, pw1;
      pw0[0] = cvtpk(p[0][0], p[0][1]); pw0[1] = cvtpk(p[0][2], p[0][3]);
      pw0[2] = cvtpk(p[1][0], p[1][1]); pw0[3] = cvtpk(p[1][2], p[1][3]);
      pw1[0] = cvtpk(p[2][0], p[2][1]); pw1[1] = cvtpk(p[2][2], p[2][3]);
      pw1[2] = cvtpk(p[3][0], p[3][1]); pw1[3] = cvtpk(p[3][2], p[3][3]);
      bf16x8 pf0 = __builtin_bit_cast(bf16x8, pw0);
      bf16x8 pf1 = __builtin_bit_cast(bf16x8, pw1);
      __builtin_amdgcn_s_setprio(1);
#pragma unroll
      for (int j = 0; j < 4; ++j) {
        oaccA[j] = __builtin_amdgcn_mfma_f32_16x16x32_bf16(vf[j][0], pf0, oaccA[j], 0, 0, 0);
        oaccA[j] = __builtin_amdgcn_mfma_f32_16x16x32_bf16(vf[j][1], pf1, oaccA[j], 0, 0, 0);
      }
      __builtin_amdgcn_s_setprio(0);
    }
    cur ^= 1;
  }

  // epilogue: reduce l for each strip, normalize, store
  lrunA += __shfl_xor(lrunA, 16);
  lrunA += __shfl_xor(lrunA, 32);
  lrunB += __shfl_xor(lrunB, 16);
  lrunB += __shfl_xor(lrunB, 32);
  float invA = 1.0f / lrunA, invB = 1.0f / lrunB;
  const int tA = tile * 128 + qlocal, tB = tile * 128 + 64 + qlocal;
#pragma unroll
  for (int j = 0; j < 4; ++j) {
    bf16x4 oA, oB;
#pragma unroll
    for (int r = 0; r < 4; ++r) {
      oA[r] = f2bf(oaccA[j][r] * invA);
      oB[r] = f2bf(oaccB[j][r] * invB);
    }
    *(bf16x4*)(Ob + (size_t)(b * T_ + tA) * D_ + h * 64 + j * 16 + lhi * 4) = oA;
    *(bf16x4*)(Ob + (size_t)(b * T_ + tB) * D_ + h * 64 + j * 16 + lhi * 4) = oB;
  }
}

extern "C" void kernel_launch(void* const* d_in, const int* in_sizes, int n_in,
                              void* d_out, int out_size, void* d_ws, size_t ws_size,
                              hipStream_t stream) {
  const float* x  = (const float*)d_in[0];
  // d_in[1] = mask (causality applied analytically)
  const float* Wq = (const float*)d_in[2];
  const float* bq = (const float*)d_in[3];
  const float* Wk = (const float*)d_in[4];
  const float* Wv = (const float*)d_in[5];
  const float* bv = (const float*)d_in[6];
  const float* Wo = (const float*)d_in[7];
  const float* bo = (const float*)d_in[8];
  float* out = (float*)d_out;

  const int MT = B_ * T_;          // 4096
  short* xb  = (short*)d_ws;                 // [4096,1024]
  short* wqb = xb  + (size_t)MT * D_;        // [3072,1024] contiguous Wq|Wk|Wv
  short* wob = wqb + (size_t)3 * D_ * D_;
  short* Qb  = wob + (size_t)D_ * D_;        // [B,H,T,HD]
  short* Kb  = Qb  + (size_t)MT * D_;
  short* Vtb = Kb  + (size_t)MT * D_;        // [B,H,HD,T] (64-col blocks permuted)
  short* Ab  = Vtb + (size_t)MT * D_;        // [4096,1024]

  cast_all<<<(8 * 1048576) / (256 * 8), 256, 0, stream>>>(x, Wq, Wk, Wv, Wo, xb);

  // fused QKV: C[4096,3072]; Q scale = 0.125 * log2(e) (base-2 softmax)
  gemm_qkv<<<(MT / 64) * 24, 256, 0, stream>>>(xb, wqb, bq, bv, Qb, Kb, Vtb);

  attn_kernel<<<B_ * H_ * 16, 256, 0, stream>>>(Qb, Kb, Vtb, Ab);

  gemm_o<<<(MT / 64) * 8, 256, 0, stream>>>(Ab, wob, bo, out);
}